// Round 4
// baseline (278.820 us; speedup 1.0000x reference)
//
#include <hip/hip_runtime.h>
#include <stdint.h>

#define C_INPUTS 41024
#define C_KEFF   40960   // last 64 cols of W are zero -> skipped exactly
#define C_L1     256
#define C_NT32   (C_KEFF / 32)                    // 1280 32-k tiles
#define WS_W_BYTES ((size_t)C_L1 * C_KEFF * 2)    // 20,971,520

typedef __attribute__((ext_vector_type(8))) short short8;
typedef __attribute__((ext_vector_type(4))) float f32x4;

__device__ __forceinline__ uint16_t bf16_rtne(float f) {
  uint32_t u = __builtin_bit_cast(uint32_t, f);
  u += 0x7fffu + ((u >> 16) & 1u);
  return (uint16_t)(u >> 16);
}

__device__ __forceinline__ short8 pack_bf16x8(float4 a, float4 b) {
  union { uint16_t h[8]; short8 v; } u;
  u.h[0] = bf16_rtne(a.x); u.h[1] = bf16_rtne(a.y);
  u.h[2] = bf16_rtne(a.z); u.h[3] = bf16_rtne(a.w);
  u.h[4] = bf16_rtne(b.x); u.h[5] = bf16_rtne(b.y);
  u.h[6] = bf16_rtne(b.z); u.h[7] = bf16_rtne(b.w);
  return u.v;
}

// ---------------------------------------------------------------------------
// Kernel 1: W [256, 41024] f32 -> bf16 workspace in FRAGMENT-MAJOR 32-k tiles.
// Tile kt: elem(kt, f, l, j) = W[16f + (l&15)][kt*32 + (l>>4)*8 + j]
// (f = 16-col group 0..15, l = frag lane, j = 0..7). The GEMM reads each
// fragment as one contiguous 1KB wave load (lane*16B) straight to VGPRs.
// ---------------------------------------------------------------------------
__global__ __launch_bounds__(256) void k_convert_w(const float* __restrict__ W,
                                                   uint16_t* __restrict__ wsW) {
  const int kt = blockIdx.x;    // 0..1279
  const int t  = threadIdx.x;
  const int l  = t & 63;
  const int fb = t >> 6;        // 0..3
  const int rm = l & 15;
  const int kg = l >> 4;        // 0..3
  const int kcol = kt * 32 + kg * 8;
  uint16_t* dst = wsW + (size_t)kt * (C_L1 * 32) + (size_t)l * 8;
#pragma unroll
  for (int q = 0; q < 4; ++q) {
    const int f = fb * 4 + q;
    const int row = f * 16 + rm;
    const float4* s = (const float4*)(W + (size_t)row * C_INPUTS + kcol);
    *(short8*)(dst + (size_t)f * 512) = pack_bf16x8(s[0], s[1]);
  }
}

// ---------------------------------------------------------------------------
// Kernel 2: GEMM. Block = (mb, ks): 64 rows x 256 cols, BK=32, NITER=80.
// 4 waves, N-split: wave w owns cols [64w,64w+64) = frags 4w..4w+3.
// W: L2 -> registers, FULL-ITER double buffer (wCur/wNext) -> the vmcnt wait
//    for W lands ~1000 cyc after issue >> L2 latency. W frags are wave-
//    private (N-split) so no LDS needed for W at all.
// A: f32 global -> regs at distance 2 -> cvt bf16 -> tiny 8KB LDS double
//    buffer (fragment slot [wave][lane] = exactly what thread loaded ->
//    lane-linear ds_write/ds_read, zero bank conflicts).
// Plain __syncthreads(); its vmcnt(0) drain only hits loads issued a full
// iteration (or two) earlier. ~19% LDS utilization, 3 blocks/CU.
// ---------------------------------------------------------------------------
template<int KSPLIT>
__global__ __launch_bounds__(256, 3) void k_gemm(const float* __restrict__ w_in,
                                                 const float* __restrict__ b_in,
                                                 const uint16_t* __restrict__ wsW,
                                                 float* __restrict__ wsP) {
  constexpr int KCHUNK = C_KEFF / KSPLIT;   // 2560 (KSPLIT=16)
  constexpr int NITER  = KCHUNK / 32;       // 80, even
  __shared__ short8 abuf[2][256];           // 2 x 4KB A tile, fragment slots

  const int bid  = blockIdx.x;
  const int ks   = bid % KSPLIT;  // XCD-affine: per-XCD W chunks fit its L2
  const int mb   = bid / KSPLIT;  // 0..63
  const int tid  = threadIdx.x;
  const int wave = tid >> 6;
  const int lane = tid & 63;
  const int lrow = lane & 15;
  const int lg   = lane >> 4;

  const float* Abase = (mb < 32) ? (w_in + (size_t)mb * 64 * C_INPUTS)
                                 : (b_in + (size_t)(mb - 32) * 64 * C_INPUTS);
  // Thread loads exactly its A-fragment slot: row wave*16+(lane&15),
  // k-group lane>>4 (8 consecutive floats).
  const float* aptr = Abase + (size_t)(wave * 16 + lrow) * C_INPUTS
                    + ks * KCHUNK + lg * 8;
  // W fragment source (fragment-major ws): frag f = wave*4 + nj.
  const uint16_t* wptr = wsW + (size_t)(ks * NITER) * 8192
                       + wave * 2048 + lane * 8;

  f32x4 acc[4][4];
#pragma unroll
  for (int i = 0; i < 4; ++i)
#pragma unroll
    for (int j = 0; j < 4; ++j) acc[i][j] = (f32x4){0.f, 0.f, 0.f, 0.f};

  float4 aA[2], aB[2];
  short8 wA[4], wB[4];

#define LOAD_A(DST, T) do {                                  \
    const float4* p_ = (const float4*)(aptr + (size_t)(T) * 32); \
    DST[0] = p_[0];                                          \
    DST[1] = p_[1];                                          \
  } while (0)

#define LOAD_W(DST, TILE) do {                               \
    const uint16_t* q_ = wptr + (size_t)(TILE) * 8192;       \
    DST[0] = *(const short8*)(q_);                           \
    DST[1] = *(const short8*)(q_ + 512);                     \
    DST[2] = *(const short8*)(q_ + 1024);                    \
    DST[3] = *(const short8*)(q_ + 1536);                    \
  } while (0)

  // ---- prologue ----
  LOAD_A(aA, 0);
  LOAD_A(aB, 1);
  LOAD_W(wA, 0);
  abuf[0][wave * 64 + lane] = pack_bf16x8(aA[0], aA[1]);
  __syncthreads();

  // STEP(T): MFMA on WC + abuf[T&1]; prefetch W(T+1)->WN, A(T+2)->AI;
  // cvt+write A(T+1) (in AC, loaded 2 iters ago) -> abuf[(T+1)&1].
#define STEP(T, WC, WN, AI, AC) do {                                            \
    if ((T) + 1 < NITER) LOAD_W(WN, (T) + 1);                                   \
    if ((T) + 2 < NITER) LOAD_A(AI, (T) + 2);                                   \
    short8 af_[4];                                                              \
    _Pragma("unroll") for (int mi = 0; mi < 4; ++mi)                            \
      af_[mi] = abuf[(T) & 1][mi * 64 + lane];                                  \
    _Pragma("unroll") for (int mi = 0; mi < 4; ++mi)                            \
      _Pragma("unroll") for (int nj = 0; nj < 4; ++nj)                          \
        acc[mi][nj] = __builtin_amdgcn_mfma_f32_16x16x32_bf16(af_[mi], WC[nj],  \
                                                              acc[mi][nj], 0, 0, 0); \
    if ((T) + 1 < NITER)                                                        \
      abuf[((T) + 1) & 1][wave * 64 + lane] = pack_bf16x8(AC[0], AC[1]);        \
    __syncthreads();                                                            \
  } while (0)

#pragma unroll 1
  for (int t = 0; t < NITER; t += 2) {
    STEP(t,     wA, wB, aA, aB);   // compute W(t);  load W(t+1)->wB, A(t+2)->aA; cvt A(t+1)=aB
    STEP(t + 1, wB, wA, aB, aA);
  }
#undef STEP
#undef LOAD_A
#undef LOAD_W

  // ---- store partials: C/D layout col=lane&15, row=(lane>>4)*4+reg ----
  float* P = wsP + ((size_t)ks * 4096 + (size_t)mb * 64) * 256;
#pragma unroll
  for (int mi = 0; mi < 4; ++mi)
#pragma unroll
    for (int nj = 0; nj < 4; ++nj)
#pragma unroll
      for (int j = 0; j < 4; ++j) {
        const int rr = mi * 16 + lg * 4 + j;
        const int cc = wave * 64 + nj * 16 + lrow;
        P[(size_t)rr * 256 + cc] = acc[mi][nj][j];
      }
}

// ---------------------------------------------------------------------------
// Kernel 3: reduce KSPLIT partials, add bias, perspective mix, clamp.
// ---------------------------------------------------------------------------
template<int KSPLIT>
__global__ __launch_bounds__(256) void k_reduce(const float* __restrict__ wsP,
                                                const float* __restrict__ us,
                                                const float* __restrict__ them,
                                                const float* __restrict__ bias,
                                                float* __restrict__ out) {
  const int r = blockIdx.x;    // 0..2047
  const int c = threadIdx.x;   // 0..255
  float wd = 0.f, bd = 0.f;
#pragma unroll
  for (int s = 0; s < KSPLIT; ++s) {
    wd += wsP[((size_t)s * 4096 + r) * 256 + c];
    bd += wsP[((size_t)s * 4096 + 2048 + r) * 256 + c];
  }
  const float bi = bias[c];
  const float w = wd + bi;
  const float b = bd + bi;
  const float u = us[r];
  const float t = them[r];
  float o1 = u * w + t * b;
  float o2 = u * b + t * w;
  o1 = fminf(fmaxf(o1, 0.f), 1.f);
  o2 = fminf(fmaxf(o2, 0.f), 1.f);
  out[(size_t)r * 512 + c]       = o1;
  out[(size_t)r * 512 + 256 + c] = o2;
}

extern "C" void kernel_launch(void* const* d_in, const int* in_sizes, int n_in,
                              void* d_out, int out_size, void* d_ws, size_t ws_size,
                              hipStream_t stream) {
  const float* us   = (const float*)d_in[0];
  const float* them = (const float*)d_in[1];
  const float* w_in = (const float*)d_in[2];
  const float* b_in = (const float*)d_in[3];
  const float* W    = (const float*)d_in[4];
  const float* bias = (const float*)d_in[5];
  float* out = (float*)d_out;

  uint16_t* wsW = (uint16_t*)d_ws;
  float*    wsP = (float*)((char*)d_ws + WS_W_BYTES);

  k_convert_w<<<C_NT32, 256, 0, stream>>>(W, wsW);

  const size_t need16 = WS_W_BYTES + (size_t)16 * 4096 * 256 * 4;  // 88.1 MB
  if (ws_size >= need16) {
    k_gemm<16><<<64 * 16, 256, 0, stream>>>(w_in, b_in, wsW, wsP);
    k_reduce<16><<<2048, 256, 0, stream>>>(wsP, us, them, bias, out);
  } else {
    k_gemm<8><<<64 * 8, 256, 0, stream>>>(w_in, b_in, wsW, wsP);
    k_reduce<8><<<2048, 256, 0, stream>>>(wsP, us, them, bias, out);
  }
}